// Round 8
// baseline (53.590 us; speedup 1.0000x reference)
//
#include <hip/hip_runtime.h>
#include <math.h>

// (b,n,h,d) = (4,8192,8,64), fp32.
// Groups: i=0: g=3,r=1,off=0,hmin=0,seg=2048  -> 8192 covered pos/b
//         i=1: g=3,r=2,off=1,hmin=3,seg=4096  -> 4096 covered pos/b (pos%2==1)
//         i=2: g=2,r=4,off=2,hmin=6,seg=8192  -> 2048 covered pos/b (pos%4==2)
#define NB 4
#define NN 8192
#define NH 8
#define ND 64
#define NPART_STRIDE 192        // per-WAVE partial: g*64 floats (max g=3)
#define N_BLOCKS_P1 448         // all co-resident: 2 blocks/CU x 256 CUs >= 448
#define N_WAVES_P1  (N_BLOCKS_P1 * 4)
#define TASKS 8                 // position-quads per wave, pipelined

// R8: persistent pipelined pass1. R7 proved MLP wasn't the limiter (9 DMAs/wave
// in flight, still 1.9 TB/s): one-shot blocks spend their life in fill/drain/
// launch transients. Now every block is co-resident for the whole kernel; each
// wave double-buffers its 9-row LDS stage and uses counted vmcnt (issue batch
// t+1, wait vmcnt(3G) -> batch t ready, t+1 still flying). No __syncthreads.

__device__ __forceinline__ void gload_lds16(const float* g, float* l) {
    __builtin_amdgcn_global_load_lds(
        (__attribute__((address_space(1))) void*)const_cast<float*>(g),
        (__attribute__((address_space(3))) void*)l, 16, 0, 0);
}

template<int G>
__device__ __forceinline__ size_t task_rowbase(
    int wave_local, int t, int sg, int l,
    int b, int r, int off, int seglen, int hmin)
{
    const int j   = (wave_local * TASKS + t) * 4 + sg;   // dilated index in (b,group)
    const int pos = (j >> 11) * seglen + off + (j & 2047) * r;
    return (((size_t)b * NN + pos) * NH + hmin) * ND + 4 * l;
}

template<int G>
__device__ __forceinline__ void issue_task(
    const float* __restrict__ Q, const float* __restrict__ K,
    const float* __restrict__ V, float* buf, size_t rowbase)
{
    #pragma unroll
    for (int q = 0; q < G; ++q) gload_lds16(Q + rowbase + q * ND, buf + q * 256);
    #pragma unroll
    for (int q = 0; q < G; ++q) gload_lds16(K + rowbase + q * ND, buf + (G + q) * 256);
    #pragma unroll
    for (int q = 0; q < G; ++q) gload_lds16(V + rowbase + q * ND, buf + (2 * G + q) * 256);
}

template<int G>
__device__ __forceinline__ void compute_task(
    const float* buf, float* __restrict__ out, size_t rowbase,
    int lane, float xs[][4])
{
    float4 qv[G], kv[G];
    #pragma unroll
    for (int q = 0; q < G; ++q) {
        qv[q] = *(const float4*)(buf + q * 256 + 4 * lane);
        kv[q] = *(const float4*)(buf + (G + q) * 256 + 4 * lane);
    }

    float sc[G][G];
    #pragma unroll
    for (int q = 0; q < G; ++q)
        #pragma unroll
        for (int k = 0; k < G; ++k)
            sc[q][k] = qv[q].x * kv[k].x + qv[q].y * kv[k].y
                     + qv[q].z * kv[k].z + qv[q].w * kv[k].w;

    // butterfly reduce across the 16 lanes of this sub-group
    #pragma unroll
    for (int o = 8; o >= 1; o >>= 1)
        #pragma unroll
        for (int q = 0; q < G; ++q)
            #pragma unroll
            for (int k = 0; k < G; ++k)
                sc[q][k] += __shfl_xor(sc[q][k], o);

    #pragma unroll
    for (int q = 0; q < G; ++q) {
        float m = -INFINITY;
        #pragma unroll
        for (int k = 0; k < G; ++k) { sc[q][k] *= 0.125f; m = fmaxf(m, sc[q][k]); }
        float ssum = 0.f;
        #pragma unroll
        for (int k = 0; k < G; ++k) { sc[q][k] = __expf(sc[q][k] - m); ssum += sc[q][k]; }
        const float rs = 1.f / ssum;
        #pragma unroll
        for (int k = 0; k < G; ++k) sc[q][k] *= rs;
    }

    float4 vv[G];
    #pragma unroll
    for (int q = 0; q < G; ++q)
        vv[q] = *(const float4*)(buf + (2 * G + q) * 256 + 4 * lane);

    #pragma unroll
    for (int q = 0; q < G; ++q) {
        float xe0 = 0.f, xe1 = 0.f, xe2 = 0.f, xe3 = 0.f;
        #pragma unroll
        for (int k = 0; k < G; ++k) {
            const float aw = sc[q][k];
            xe0 += aw * vv[k].x; xe1 += aw * vv[k].y;
            xe2 += aw * vv[k].z; xe3 += aw * vv[k].w;
        }
        *(float4*)(out + rowbase + (size_t)q * ND) = make_float4(xe0, xe1, xe2, xe3);
        xs[q][0] += xe0; xs[q][1] += xe1; xs[q][2] += xe2; xs[q][3] += xe3;
    }
}

template<int G>
__device__ __forceinline__ void pass1_work(
    const float* __restrict__ Q, const float* __restrict__ K,
    const float* __restrict__ V, float* __restrict__ out,
    float* __restrict__ partials, float* st /* this wave's 2x9x256 stage */,
    int b, int block_local, int wid_base,
    int r, int off, int hmin, int seglen)
{
    const int tid  = threadIdx.x;   // 256 threads = 4 waves, fully independent
    const int w    = tid >> 6;
    const int lane = tid & 63;
    const int sg   = lane >> 4;     // 16-lane sub-group = one position
    const int l    = lane & 15;     // lane owns d in [4l, 4l+4)

    const int wave_local = block_local * 4 + w;   // within (b, group)

    float xs[G][4];
    #pragma unroll
    for (int q = 0; q < G; ++q)
        #pragma unroll
        for (int e = 0; e < 4; ++e) xs[q][e] = 0.f;

    // prologue: fill stage 0
    issue_task<G>(Q, K, V, st,
                  task_rowbase<G>(wave_local, 0, sg, l, b, r, off, seglen, hmin));

    for (int t = 0; t < TASKS - 1; ++t) {
        // issue next batch into the other buffer (kept in flight across the wait)
        issue_task<G>(Q, K, V, st + ((t + 1) & 1) * (9 * 256),
                      task_rowbase<G>(wave_local, t + 1, sg, l, b, r, off, seglen, hmin));
        // drain batch t (+ old stores); leave the 3G newest (batch t+1) flying
        asm volatile("s_waitcnt vmcnt(%0)" :: "i"(3 * G) : "memory");
        __builtin_amdgcn_sched_barrier(0);
        compute_task<G>(st + (t & 1) * (9 * 256), out,
                        task_rowbase<G>(wave_local, t, sg, l, b, r, off, seglen, hmin),
                        lane, xs);
    }
    asm volatile("s_waitcnt vmcnt(0)" ::: "memory");
    __builtin_amdgcn_sched_barrier(0);
    compute_task<G>(st + ((TASKS - 1) & 1) * (9 * 256), out,
                    task_rowbase<G>(wave_local, TASKS - 1, sg, l, b, r, off, seglen, hmin),
                    lane, xs);

    // wave-level reduction across the 4 sub-groups (register-only)
    #pragma unroll
    for (int q = 0; q < G; ++q)
        #pragma unroll
        for (int e = 0; e < 4; ++e) {
            xs[q][e] += __shfl_xor(xs[q][e], 16);
            xs[q][e] += __shfl_xor(xs[q][e], 32);
        }

    if (lane < 16) {
        const int wid = wid_base + w;
        #pragma unroll
        for (int q = 0; q < G; ++q)
            *(float4*)(partials + (size_t)wid * NPART_STRIDE + q * 64 + 4 * l) =
                make_float4(xs[q][0], xs[q][1], xs[q][2], xs[q][3]);
    }
}

__global__ __launch_bounds__(256)
void sda_pass1(const float* __restrict__ Q, const float* __restrict__ K,
               const float* __restrict__ V, float* __restrict__ out,
               float* __restrict__ partials)
{
    __shared__ float stage[4][2][9][256];   // 72 KB: 4 waves x dbuf x 9 rows x 1KB
    float* st = &stage[threadIdx.x >> 6][0][0][0];
    const int bid = blockIdx.x;
    if (bid < 256) {                       // group 0: 4 b * 64 blocks
        const int b = bid >> 6, bl = bid & 63;
        pass1_work<3>(Q, K, V, out, partials, st, b, bl,
                      (bid) * 4, 1, 0, 0, 2048);
    } else if (bid < 384) {                // group 1: 4 b * 32 blocks
        const int loc = bid - 256;
        const int b = loc >> 5, bl = loc & 31;
        pass1_work<3>(Q, K, V, out, partials, st, b, bl,
                      bid * 4, 2, 1, 3, 4096);
    } else {                               // group 2: 4 b * 16 blocks
        const int loc = bid - 384;
        const int b = loc >> 4, bl = loc & 15;
        pass1_work<2>(Q, K, V, out, partials, st, b, bl,
                      bid * 4, 4, 2, 6, 8192);
    }
}

// pass2a: 256 blocks = (bh 0..31) x (slice 0..7); coalesced wave-partial reduce.
__global__ __launch_bounds__(256)
void sda_pass2a(const float* __restrict__ partials, float* __restrict__ partial2)
{
    const int bid   = blockIdx.x;
    const int bh    = bid >> 3;
    const int slice = bid & 7;
    const int b     = bh >> 3;
    const int h     = bh & 7;
    const int d     = threadIdx.x & 63;
    const int part  = threadIdx.x >> 6;   // 4-way split of the slice
    int qi, wstart, cnt;
    if (h < 3)      { qi = h;     wstart = b * 256;        cnt = 256; }
    else if (h < 6) { qi = h - 3; wstart = 1024 + b * 128; cnt = 128; }
    else            { qi = h - 6; wstart = 1536 + b * 64;  cnt = 64;  }
    const int len = cnt >> 3;             // 32 / 16 / 8
    const int c0  = wstart + slice * len;
    float s = 0.f;
    #pragma unroll 4
    for (int c = part; c < len; c += 4)
        s += partials[(size_t)(c0 + c) * NPART_STRIDE + qi * 64 + d];
    __shared__ float sred[4][64];
    sred[part][d] = s;
    __syncthreads();
    if (part == 0)
        partial2[(size_t)bid * 64 + d] = sred[0][d] + sred[1][d] + sred[2][d] + sred[3][d];
}

// pass2b: finish 8 slice-partials per (b,h,d) -> inv
__global__ __launch_bounds__(256)
void sda_pass2b(const float* __restrict__ partial2, float* __restrict__ inv)
{
    const int t = blockIdx.x * 256 + threadIdx.x;   // 2048 = bh*64 + d
    if (t >= NB * NH * ND) return;
    const int bh = t >> 6;
    const int d  = t & 63;
    float s = 0.f;
    #pragma unroll
    for (int sl = 0; sl < 8; ++sl)
        s += partial2[(size_t)(bh * 8 + sl) * 64 + d];
    inv[t] = 1.f / (3.f * (s + 1e-8f));
}

__global__ __launch_bounds__(256)
void sda_pass3(float* __restrict__ out, const float* __restrict__ inv)
{
    const int total4 = NB * NN * NH * ND / 4;   // 4,194,304 float4s
    for (int idx = blockIdx.x * 256 + threadIdx.x; idx < total4;
         idx += gridDim.x * 256) {
        const int d4  = idx & 15;
        const int rem = idx >> 4;
        const int h   = rem & 7;
        const int pos = (rem >> 3) & 8191;
        const int b   = rem >> 16;
        const bool cov = (h < 3) || ((h < 6) ? ((pos & 1) == 1) : ((pos & 3) == 2));
        float4 o;
        if (cov) {
            const float4 v = ((const float4*)out)[idx];
            const float4 f = ((const float4*)inv)[b * 128 + h * 16 + d4];
            o = make_float4(v.x * f.x, v.y * f.y, v.z * f.z, v.w * f.w);
        } else {
            o = make_float4(0.f, 0.f, 0.f, 0.f);
        }
        ((float4*)out)[idx] = o;
    }
}

extern "C" void kernel_launch(void* const* d_in, const int* in_sizes, int n_in,
                              void* d_out, int out_size, void* d_ws, size_t ws_size,
                              hipStream_t stream)
{
    const float* Q = (const float*)d_in[0];
    const float* K = (const float*)d_in[1];
    const float* V = (const float*)d_in[2];
    float* out      = (float*)d_out;
    float* partials = (float*)d_ws;                              // 1792*192*4 ≈ 1.4 MB
    float* partial2 = partials + (size_t)N_WAVES_P1 * NPART_STRIDE; // +16384 floats
    float* inv      = partial2 + 256 * 64;                       // +2048 floats

    hipLaunchKernelGGL(sda_pass1,  dim3(N_BLOCKS_P1), dim3(256), 0, stream,
                       Q, K, V, out, partials);
    hipLaunchKernelGGL(sda_pass2a, dim3(256), dim3(256), 0, stream, partials, partial2);
    hipLaunchKernelGGL(sda_pass2b, dim3(8),   dim3(256), 0, stream, partial2, inv);
    hipLaunchKernelGGL(sda_pass3,  dim3(2048), dim3(256), 0, stream, out, inv);
}